// Round 5
// baseline (832.657 us; speedup 1.0000x reference)
//
#include <hip/hip_runtime.h>
#include <cstddef>
#include <cstdint>

// Problem constants (from reference): B,L,H,E,N,TR,K
constexpr int B_  = 2;
constexpr int L_  = 1024;
constexpr int H_  = 2048;
constexpr int E_  = 4096;
constexpr int N_  = 16;
constexpr int TR_ = 128;
constexpr int M_  = B_ * L_;        // 2048 token rows
constexpr int P2E = 2 * E_;         // 8192  (proj leading dim)
constexpr int SLD = TR_ + 2 * N_;   // 160   (ssm_p leading dim)
constexpr int CH_ = 32;             // scan chunks along L
constexpr int CL_ = L_ / CH_;       // 32 steps per chunk

typedef unsigned short u16;
using short8 = __attribute__((ext_vector_type(8))) short;
using f32x4  = __attribute__((ext_vector_type(4))) float;

__device__ __forceinline__ float siluf(float x) { return x / (1.f + expf(-x)); }
__device__ __forceinline__ float silu_fast(float x) { return x / (1.f + __expf(-x)); }
__device__ __forceinline__ float softplusf(float x) {
  return fmaxf(x, 0.f) + log1pf(expf(-fabsf(x)));
}
__device__ __forceinline__ u16 f2bf(float x) {
  union { float f; uint32_t u; } v; v.f = x;
  uint32_t r = v.u + 0x7FFFu + ((v.u >> 16) & 1u);   // RNE
  return (u16)(r >> 16);
}
__device__ __forceinline__ float bf2f(u16 h) {
  union { uint32_t u; float f; } v; v.u = ((uint32_t)h) << 16; return v.f;
}
// async global->LDS, 16B per lane; dest = wave-uniform base + lane*16
__device__ __forceinline__ void gll16(const u16* g, u16* l) {
  __builtin_amdgcn_global_load_lds(
      (const __attribute__((address_space(1))) void*)(const void*)g,
      (__attribute__((address_space(3))) void*)(void*)l, 16, 0, 0);
}

// ---------------------------------------------------------------------------
// fp32 tiled GEMM (x-proj, dt-proj, and full-pipeline fallback)
// ---------------------------------------------------------------------------
template<int BM, int BN, int BK, int TM, int TN, int EPI>
__global__ __launch_bounds__(256) void sgemm_k(
    const float* __restrict__ A, const float* __restrict__ B,
    float* __restrict__ C, int lda, int ldb, int ldc,
    const float* __restrict__ bias, int kchunk)
{
  __shared__ float As[BK][BM + 4];
  __shared__ float Bs[BK][BN];
  const int tid = threadIdx.x;
  const int tx  = tid & 15;
  const int ty  = tid >> 4;
  const int m0  = blockIdx.y * BM;
  const int n0  = blockIdx.x * BN;
  const int k00 = blockIdx.z * kchunk;

  float acc[TM][TN];
#pragma unroll
  for (int i = 0; i < TM; ++i)
#pragma unroll
    for (int j = 0; j < TN; ++j) acc[i][j] = 0.f;

  for (int k0 = k00; k0 < k00 + kchunk; k0 += BK) {
    constexpr int A4 = BM * BK / 4;
#pragma unroll
    for (int it = 0; it < (A4 + 255) / 256; ++it) {
      int i = it * 256 + tid;
      if ((A4 % 256 == 0) || (i < A4)) {
        int row = i / (BK / 4);
        int kc  = (i % (BK / 4)) * 4;
        float4 v = *reinterpret_cast<const float4*>(
            A + (size_t)(m0 + row) * lda + k0 + kc);
        As[kc + 0][row] = v.x; As[kc + 1][row] = v.y;
        As[kc + 2][row] = v.z; As[kc + 3][row] = v.w;
      }
    }
    constexpr int B4 = BK * BN / 4;
#pragma unroll
    for (int it = 0; it < (B4 + 255) / 256; ++it) {
      int i = it * 256 + tid;
      if ((B4 % 256 == 0) || (i < B4)) {
        int kr = i / (BN / 4);
        int nc = (i % (BN / 4)) * 4;
        *reinterpret_cast<float4*>(&Bs[kr][nc]) =
            *reinterpret_cast<const float4*>(
                B + (size_t)(k0 + kr) * ldb + n0 + nc);
      }
    }
    __syncthreads();
#pragma unroll
    for (int k = 0; k < BK; ++k) {
      float a[TM], bb[TN];
      const float* ap = &As[k][ty * TM];
      if constexpr (TM == 8) {
        float4 a0 = *reinterpret_cast<const float4*>(ap);
        float4 a1 = *reinterpret_cast<const float4*>(ap + 4);
        a[0]=a0.x; a[1]=a0.y; a[2]=a0.z; a[3]=a0.w;
        a[4]=a1.x; a[5]=a1.y; a[6]=a1.z; a[7]=a1.w;
      } else {
        float4 a0 = *reinterpret_cast<const float4*>(ap);
        a[0]=a0.x; a[1]=a0.y; a[2]=a0.z; a[3]=a0.w;
      }
      const float* bp = &Bs[k][tx * TN];
      if constexpr (TN == 4) {
        float4 b0 = *reinterpret_cast<const float4*>(bp);
        bb[0]=b0.x; bb[1]=b0.y; bb[2]=b0.z; bb[3]=b0.w;
      } else {
        float2 b0 = *reinterpret_cast<const float2*>(bp);
        bb[0]=b0.x; bb[1]=b0.y;
      }
#pragma unroll
      for (int i = 0; i < TM; ++i)
#pragma unroll
        for (int j = 0; j < TN; ++j) acc[i][j] = fmaf(a[i], bb[j], acc[i][j]);
    }
    __syncthreads();
  }

#pragma unroll
  for (int i = 0; i < TM; ++i) {
    int row = m0 + ty * TM + i;
    float* crow = C + (size_t)row * ldc + n0 + tx * TN;
    if constexpr (EPI == 2) {
#pragma unroll
      for (int j = 0; j < TN; ++j) atomicAdd(&crow[j], acc[i][j]);
    } else if constexpr (EPI == 1) {
      const float* brow = bias + n0 + tx * TN;
      float4 v;
      v.x = softplusf(acc[i][0] + brow[0]);
      v.y = softplusf(acc[i][1] + brow[1]);
      v.z = softplusf(acc[i][2] + brow[2]);
      v.w = softplusf(acc[i][3] + brow[3]);
      *reinterpret_cast<float4*>(crow) = v;
    } else {
      if constexpr (TN == 4) {
        float4 v; v.x=acc[i][0]; v.y=acc[i][1]; v.z=acc[i][2]; v.w=acc[i][3];
        *reinterpret_cast<float4*>(crow) = v;
      } else {
#pragma unroll
        for (int j = 0; j < TN; ++j) crow[j] = acc[i][j];
      }
    }
  }
}

// ---------------------------------------------------------------------------
// fp32 -> (bf16 hi, bf16 lo), row-major passthrough. 4 floats / thread.
// ---------------------------------------------------------------------------
__global__ __launch_bounds__(256) void decomp_k(
    const float* __restrict__ in, u16* __restrict__ hi, u16* __restrict__ lo,
    int n4)
{
  int i = blockIdx.x * 256 + threadIdx.x;
  if (i >= n4) return;
  float4 v = *reinterpret_cast<const float4*>(in + (size_t)i * 4);
  u16 h[4], l[4];
  float x[4] = {v.x, v.y, v.z, v.w};
#pragma unroll
  for (int j = 0; j < 4; ++j) {
    h[j] = f2bf(x[j]);
    l[j] = f2bf(x[j] - bf2f(h[j]));
  }
  uint32_t h0 = h[0] | ((uint32_t)h[1] << 16), h1 = h[2] | ((uint32_t)h[3] << 16);
  uint32_t l0 = l[0] | ((uint32_t)l[1] << 16), l1 = l[2] | ((uint32_t)l[3] << 16);
  *reinterpret_cast<uint2*>(hi + (size_t)i * 4) = make_uint2(h0, h1);
  *reinterpret_cast<uint2*>(lo + (size_t)i * 4) = make_uint2(l0, l1);
}

// ---------------------------------------------------------------------------
// W[KD][ND] fp32 -> Wt_hi/Wt_lo [ND][KD] bf16 (transpose + decompose).
// ---------------------------------------------------------------------------
__global__ __launch_bounds__(256) void wdecomp_t_k(
    const float* __restrict__ W, u16* __restrict__ Whi, u16* __restrict__ Wlo,
    int KD, int ND)
{
  __shared__ float T[64][69];
  const int t  = threadIdx.x;
  const int n0 = blockIdx.x * 64;
  const int k0 = blockIdx.y * 64;
#pragma unroll
  for (int it = 0; it < 4; ++it) {
    int f  = it * 256 + t;
    int kk = f >> 4;
    int c  = (f & 15) * 4;
    float4 v = *reinterpret_cast<const float4*>(
        W + (size_t)(k0 + kk) * ND + n0 + c);
    T[kk][c] = v.x; T[kk][c+1] = v.y; T[kk][c+2] = v.z; T[kk][c+3] = v.w;
  }
  __syncthreads();
  const int nn   = t >> 2;
  const int kseg = (t & 3) * 16;
  const size_t off = (size_t)(n0 + nn) * KD + k0 + kseg;
#pragma unroll
  for (int half = 0; half < 2; ++half) {
    uint32_t hp[4], lp[4];
#pragma unroll
    for (int jj = 0; jj < 4; ++jj) {
      float x0 = T[kseg + half * 8 + jj * 2 + 0][nn];
      float x1 = T[kseg + half * 8 + jj * 2 + 1][nn];
      u16 h0 = f2bf(x0), h1 = f2bf(x1);
      u16 l0 = f2bf(x0 - bf2f(h0)), l1 = f2bf(x1 - bf2f(h1));
      hp[jj] = h0 | ((uint32_t)h1 << 16);
      lp[jj] = l0 | ((uint32_t)l1 << 16);
    }
    *reinterpret_cast<uint4*>(Whi + off + half * 8) =
        make_uint4(hp[0], hp[1], hp[2], hp[3]);
    *reinterpret_cast<uint4*>(Wlo + off + half * 8) =
        make_uint4(lp[0], lp[1], lp[2], lp[3]);
  }
}

// ---------------------------------------------------------------------------
// Split-bf16 MFMA GEMM: C[M][N] fp32 = A[M][K] x Bt[N][K]^T via
//   Ah*Bh + Ah*Bl + Al*Bh (3x mfma_f32_16x16x32_bf16, fp32 accumulate).
// 128x128 tile, BK=32. Staging via global_load_lds (width 16, linear LDS),
// XOR swizzle realized on the SOURCE address + fragment-read offset
// (Guideline 21: both-sides-or-neither). Conflict-free reads AND writes.
// 1D grid with bijective XCD swizzle (tm-fast -> B k-stripe reuse per XCD).
// ---------------------------------------------------------------------------
__global__ __launch_bounds__(256) void gemm3bf_k(
    const u16* __restrict__ Ah, const u16* __restrict__ Al,
    const u16* __restrict__ Bh, const u16* __restrict__ Bl,
    float* __restrict__ C, int K, int ldc)
{
  __shared__ __align__(16) u16 sAh[128 * 32];
  __shared__ __align__(16) u16 sAl[128 * 32];
  __shared__ __align__(16) u16 sBh[128 * 32];
  __shared__ __align__(16) u16 sBl[128 * 32];

  const int tid  = threadIdx.x;
  const int lane = tid & 63;
  const int wid  = tid >> 6;
  const int wr   = wid >> 1, wc = wid & 1;

  // XCD-aware bijective swizzle (gridDim.x % 8 == 0 at both call sites)
  const int nwg = gridDim.x;
  const int q8  = nwg >> 3;
  const int wg  = (blockIdx.x & 7) * q8 + (blockIdx.x >> 3);
  const int tm  = wg & 15;          // nTm = M_/128 = 16 (fixed)
  const int tn  = wg >> 4;
  const int m0  = tm * 128;
  const int n0  = tn * 128;

  // ---- staging geometry (global_load_lds) ----
  // wave w stages rows [w*16, w*16+16) and [64+w*16, ...) of each buffer.
  // lane l -> row +(l>>2), PHYSICAL slot l&3; logical slot s = (l&3)^((l>>3)&3)
  // (LDS layout: phys_slot = logical_slot ^ ((row>>1)&3), row stride 64 B)
  const int dr = lane >> 2;
  const int sw = (lane & 3) ^ ((lane >> 3) & 3);
  const int r1 = wid * 16 + dr;
  const int r2 = r1 + 64;

  const u16* ga1 = Ah + (size_t)(m0 + r1) * K + sw * 8;
  const u16* ga2 = Ah + (size_t)(m0 + r2) * K + sw * 8;
  const u16* gl1 = Al + (size_t)(m0 + r1) * K + sw * 8;
  const u16* gl2 = Al + (size_t)(m0 + r2) * K + sw * 8;
  const u16* gb1 = Bh + (size_t)(n0 + r1) * K + sw * 8;
  const u16* gb2 = Bh + (size_t)(n0 + r2) * K + sw * 8;
  const u16* gc1 = Bl + (size_t)(n0 + r1) * K + sw * 8;
  const u16* gc2 = Bl + (size_t)(n0 + r2) * K + sw * 8;

  u16* dA1 = sAh + (wid * 16) * 32;
  u16* dA2 = sAh + (64 + wid * 16) * 32;
  u16* dL1 = sAl + (wid * 16) * 32;
  u16* dL2 = sAl + (64 + wid * 16) * 32;
  u16* dB1 = sBh + (wid * 16) * 32;
  u16* dB2 = sBh + (64 + wid * 16) * 32;
  u16* dC1 = sBl + (wid * 16) * 32;
  u16* dC2 = sBl + (64 + wid * 16) * 32;

  // ---- fragment-read offsets (swizzled) ----
  const int fr = lane & 15;
  const int ph = (lane >> 4) ^ ((fr >> 1) & 3);    // physical 16B slot
  const int offA = (wr * 64 + fr) * 32 + ph * 8;   // u16 index; + mr*512
  const int offB = (wc * 64 + fr) * 32 + ph * 8;   // u16 index; + nc*512

  f32x4 acc[4][4] = {};

  for (int k0 = 0; k0 < K; k0 += 32) {
    __syncthreads();                  // prev tile's ds_reads done
    gll16(ga1 + k0, dA1);  gll16(ga2 + k0, dA2);
    gll16(gl1 + k0, dL1);  gll16(gl2 + k0, dL2);
    gll16(gb1 + k0, dB1);  gll16(gb2 + k0, dB2);
    gll16(gc1 + k0, dC1);  gll16(gc2 + k0, dC2);
    __syncthreads();                  // drains vmcnt(0): staging complete

    short8 bhf[4], blf[4];
#pragma unroll
    for (int nc = 0; nc < 4; ++nc) {
      bhf[nc] = *reinterpret_cast<const short8*>(&sBh[offB + nc * 512]);
      blf[nc] = *reinterpret_cast<const short8*>(&sBl[offB + nc * 512]);
    }
#pragma unroll
    for (int mr = 0; mr < 4; ++mr) {
      short8 ahf = *reinterpret_cast<const short8*>(&sAh[offA + mr * 512]);
      short8 alf = *reinterpret_cast<const short8*>(&sAl[offA + mr * 512]);
#pragma unroll
      for (int nc = 0; nc < 4; ++nc) {
        acc[mr][nc] = __builtin_amdgcn_mfma_f32_16x16x32_bf16(ahf, bhf[nc], acc[mr][nc], 0, 0, 0);
        acc[mr][nc] = __builtin_amdgcn_mfma_f32_16x16x32_bf16(ahf, blf[nc], acc[mr][nc], 0, 0, 0);
        acc[mr][nc] = __builtin_amdgcn_mfma_f32_16x16x32_bf16(alf, bhf[nc], acc[mr][nc], 0, 0, 0);
      }
    }
  }

  // epilogue: C/D layout col=lane&15, row=(lane>>4)*4+i   [m89-verified]
#pragma unroll
  for (int mr = 0; mr < 4; ++mr) {
    const int rowb = m0 + wr * 64 + mr * 16 + ((lane >> 4) << 2);
#pragma unroll
    for (int nc = 0; nc < 4; ++nc) {
      const int col = n0 + wc * 64 + nc * 16 + fr;
      float* cp = C + (size_t)rowb * ldc + col;
#pragma unroll
      for (int i = 0; i < 4; ++i) cp[(size_t)i * ldc] = acc[mr][nc][i];
    }
  }
}

// ---------------------------------------------------------------------------
// Depthwise causal conv1d (K=4) + bias + SiLU
// ---------------------------------------------------------------------------
__global__ __launch_bounds__(256) void conv_silu_k(
    const float* __restrict__ proj, const float* __restrict__ ck,
    const float* __restrict__ cb, float* __restrict__ hc)
{
  const int idx = blockIdx.x * 256 + threadIdx.x;
  const int e = idx & (E_ - 1);
  const int m = idx >> 12;
  const int l = m & (L_ - 1);
  const float c0 = ck[e * 4 + 0], c1 = ck[e * 4 + 1];
  const float c2 = ck[e * 4 + 2], c3 = ck[e * 4 + 3];
  const float* pcol = proj + (size_t)m * P2E + e;
  float acc = cb[e];
  if (l >= 3) acc = fmaf(pcol[-3 * P2E], c0, acc);
  if (l >= 2) acc = fmaf(pcol[-2 * P2E], c1, acc);
  if (l >= 1) acc = fmaf(pcol[-1 * P2E], c2, acc);
  acc = fmaf(pcol[0], c3, acc);
  hc[(size_t)m * E_ + e] = siluf(acc);
}

// ---------------------------------------------------------------------------
// Chunked selective scan, thread = e-channel, all N=16 states in registers.
// ---------------------------------------------------------------------------
__global__ __launch_bounds__(256) void scan_p1_k(
    const float* __restrict__ hc, const float* __restrict__ ssm,
    const float* __restrict__ A_log, const float* __restrict__ dts,
    float* __restrict__ Pbuf, float* __restrict__ Qbuf)
{
  __shared__ float sB[CL_][16];
  const int tid = threadIdx.x;
  const int bid = blockIdx.x;
  const int e   = ((bid & 15) << 8) + tid;
  const int c   = (bid >> 4) & (CH_ - 1);
  const int b   = bid >> 9;
  const int m0  = b * L_ + c * CL_;

  if (tid < CL_ * 4) {
    int s = tid >> 2, q = tid & 3;
    *reinterpret_cast<float4*>(&sB[s][q * 4]) =
        *reinterpret_cast<const float4*>(
            &ssm[(size_t)(m0 + s) * SLD + TR_ + q * 4]);
  }
  __syncthreads();

  float Aen[N_];
#pragma unroll
  for (int q = 0; q < 4; ++q) {
    float4 av = *reinterpret_cast<const float4*>(&A_log[e * N_ + q * 4]);
    Aen[q*4+0] = -expf(av.x); Aen[q*4+1] = -expf(av.y);
    Aen[q*4+2] = -expf(av.z); Aen[q*4+3] = -expf(av.w);
  }

  float P[N_], Q[N_];
#pragma unroll
  for (int n = 0; n < N_; ++n) { P[n] = 1.f; Q[n] = 0.f; }

  float dt_c = dts[(size_t)m0 * E_ + e];
  float h_c  = hc [(size_t)m0 * E_ + e];
  for (int s = 0; s < CL_; ++s) {
    const int sn = (s + 1 < CL_) ? s + 1 : s;
    const float dt_n = dts[(size_t)(m0 + sn) * E_ + e];
    const float h_n  = hc [(size_t)(m0 + sn) * E_ + e];
    const float dth = dt_c * h_c;
#pragma unroll
    for (int q = 0; q < 4; ++q) {
      const float4 bv = *reinterpret_cast<const float4*>(&sB[s][q * 4]);
      const float bx[4] = {bv.x, bv.y, bv.z, bv.w};
#pragma unroll
      for (int j = 0; j < 4; ++j) {
        const int n = q * 4 + j;
        const float a = __expf(dt_c * Aen[n]);
        Q[n] = fmaf(a, Q[n], dth * bx[j]);
        P[n] *= a;
      }
    }
    dt_c = dt_n; h_c = h_n;
  }

  const size_t ob = (((size_t)b * CH_ + c) * N_) * E_ + e;
#pragma unroll
  for (int n = 0; n < N_; ++n) {
    Pbuf[ob + (size_t)n * E_] = P[n];
    Qbuf[ob + (size_t)n * E_] = Q[n];
  }
}

__global__ __launch_bounds__(256) void scan_p3_k(
    const float* __restrict__ hc, const float* __restrict__ ssm,
    const float* __restrict__ proj, const float* __restrict__ A_log,
    const float* __restrict__ Dvec, const float* __restrict__ dts,
    const float* __restrict__ Pbuf, const float* __restrict__ Qbuf,
    u16* __restrict__ yhi, u16* __restrict__ ylo)
{
  __shared__ float sBC[CL_][32];
  const int tid = threadIdx.x;
  const int bid = blockIdx.x;
  const int e   = ((bid & 15) << 8) + tid;
  const int c   = (bid >> 4) & (CH_ - 1);
  const int b   = bid >> 9;
  const int m0  = b * L_ + c * CL_;

  {
    int s = tid >> 3, q = tid & 7;
    *reinterpret_cast<float4*>(&sBC[s][q * 4]) =
        *reinterpret_cast<const float4*>(
            &ssm[(size_t)(m0 + s) * SLD + TR_ + q * 4]);
  }
  __syncthreads();

  float Aen[N_];
#pragma unroll
  for (int q = 0; q < 4; ++q) {
    float4 av = *reinterpret_cast<const float4*>(&A_log[e * N_ + q * 4]);
    Aen[q*4+0] = -expf(av.x); Aen[q*4+1] = -expf(av.y);
    Aen[q*4+2] = -expf(av.z); Aen[q*4+3] = -expf(av.w);
  }
  const float De = Dvec[e];

  float st[N_];
#pragma unroll
  for (int n = 0; n < N_; ++n) st[n] = 0.f;
  for (int cc = 0; cc < c; ++cc) {
    const size_t ob = (((size_t)b * CH_ + cc) * N_) * E_ + e;
#pragma unroll
    for (int n = 0; n < N_; ++n)
      st[n] = fmaf(Pbuf[ob + (size_t)n * E_], st[n], Qbuf[ob + (size_t)n * E_]);
  }

  float dt_c = dts[(size_t)m0 * E_ + e];
  float h_c  = hc [(size_t)m0 * E_ + e];
  float g_c  = proj[(size_t)m0 * P2E + E_ + e];
  for (int s = 0; s < CL_; ++s) {
    const int sn = (s + 1 < CL_) ? s + 1 : s;
    const float dt_n = dts[(size_t)(m0 + sn) * E_ + e];
    const float h_n  = hc [(size_t)(m0 + sn) * E_ + e];
    const float g_n  = proj[(size_t)(m0 + sn) * P2E + E_ + e];
    const float dth = dt_c * h_c;
    float y = h_c * De;
#pragma unroll
    for (int q = 0; q < 4; ++q) {
      const float4 bv = *reinterpret_cast<const float4*>(&sBC[s][q * 4]);
      const float4 cv = *reinterpret_cast<const float4*>(&sBC[s][16 + q * 4]);
      const float bx[4] = {bv.x, bv.y, bv.z, bv.w};
      const float cx[4] = {cv.x, cv.y, cv.z, cv.w};
#pragma unroll
      for (int j = 0; j < 4; ++j) {
        const int n = q * 4 + j;
        const float a = __expf(dt_c * Aen[n]);
        st[n] = fmaf(a, st[n], dth * bx[j]);
        y = fmaf(st[n], cx[j], y);
      }
    }
    const float res = y * silu_fast(g_c);
    const u16 hv = f2bf(res);
    const size_t yo = (size_t)(m0 + s) * E_ + e;
    yhi[yo] = hv;
    ylo[yo] = f2bf(res - bf2f(hv));
    dt_c = dt_n; h_c = h_n; g_c = g_n;
  }
}

// fp32-output serial scan (fallback path only)
__global__ __launch_bounds__(256) void scan_serial_k(
    const float* __restrict__ hc, const float* __restrict__ ssm,
    const float* __restrict__ proj, const float* __restrict__ A_log,
    const float* __restrict__ Dvec, const float* __restrict__ dts,
    float* __restrict__ yf)
{
  const int tid = threadIdx.x;
  const int n  = tid & 15;
  const int ge = blockIdx.x * 16 + (tid >> 4);
  const int b  = ge >> 12;
  const int e  = ge & (E_ - 1);
  const float Aen = -expf(A_log[e * N_ + n]);
  const float De  = Dvec[e];
  float state = 0.f;
  const int mbase = b * L_;
  for (int l = 0; l < L_; ++l) {
    const int m = mbase + l;
    const float dt = dts[(size_t)m * E_ + e];
    const float h  = hc[(size_t)m * E_ + e];
    const float Bm = ssm[(size_t)m * SLD + TR_ + n];
    const float Cm = ssm[(size_t)m * SLD + TR_ + N_ + n];
    state = fmaf(expf(dt * Aen), state, dt * Bm * h);
    float yp = state * Cm;
    yp += __shfl_xor(yp, 1);
    yp += __shfl_xor(yp, 2);
    yp += __shfl_xor(yp, 4);
    yp += __shfl_xor(yp, 8);
    const float g   = proj[(size_t)m * P2E + E_ + e];
    const float res = (yp + h * De) * siluf(g);
    if (n == 0) yf[(size_t)m * E_ + e] = res;
  }
}

// ---------------------------------------------------------------------------
extern "C" void kernel_launch(void* const* d_in, const int* in_sizes, int n_in,
                              void* d_out, int out_size, void* d_ws, size_t ws_size,
                              hipStream_t stream)
{
  const float* x_in  = (const float*)d_in[0];
  const float* W_in  = (const float*)d_in[1];
  const float* ck    = (const float*)d_in[2];
  const float* cb    = (const float*)d_in[3];
  const float* W_x   = (const float*)d_in[4];
  const float* W_dt  = (const float*)d_in[5];
  const float* b_dt  = (const float*)d_in[6];
  const float* W_out = (const float*)d_in[7];
  const float* A_log = (const float*)d_in[8];
  const float* Dvec  = (const float*)d_in[9];
  float* out = (float*)d_out;
  float* ws  = (float*)d_ws;

  // common fp32 workspace
  float* proj = ws;                               // 16,777,216 f (64 MB)
  float* hc   = proj + (size_t)M_ * P2E;          // 8,388,608  f (32 MB)
  float* dts  = hc   + (size_t)M_ * E_;           // 8,388,608  f (32 MB)
  float* ssm  = dts  + (size_t)M_ * E_;           // 327,680    f (1.25 MB)

  // bf16 regions, lifetime-aliased:
  //  regA (32 MB): x_hi/x_lo (dead after in-proj)  -> Wo_hi/Wo_lo
  //  regB (64 MB): Wi_hi/Wi_lo (dead after in-proj) -> y_hi/y_lo (0..32MB)
  //                                                  + Pbuf/Qbuf (32..64MB)
  u16* regA  = (u16*)(ssm + (size_t)M_ * SLD);
  u16* x_hi  = regA;
  u16* x_lo  = regA + (size_t)M_ * H_;
  u16* Wo_hi = regA;
  u16* Wo_lo = regA + (size_t)H_ * E_;
  u16* regB  = regA + 16777216;
  u16* Wi_hi = regB;
  u16* Wi_lo = regB + (size_t)P2E * H_;
  u16* y_hi  = regB;
  u16* y_lo  = regB + (size_t)M_ * E_;
  float* Pbuf = (float*)(regB + 16777216);         // 4,194,304 f (16 MB)
  float* Qbuf = Pbuf + (size_t)B_ * CH_ * E_ * N_; // 4,194,304 f (16 MB)

  const size_t need_bf =
      ((size_t)M_ * P2E + 2 * (size_t)M_ * E_ + (size_t)M_ * SLD) * 4 +
      (16777216ULL + 33554432ULL) * 2;            // = 236,191,744 B

  // x-proj accumulates with split-K atomics -> zero it every call
  hipMemsetAsync(ssm, 0, (size_t)M_ * SLD * sizeof(float), stream);

  if (ws_size >= need_bf) {
    // ---- split-bf16 MFMA path + register-state chunked scan ----
    decomp_k<<<(M_ * H_ / 4 + 255) / 256, 256, 0, stream>>>(
        x_in, x_hi, x_lo, M_ * H_ / 4);
    wdecomp_t_k<<<dim3(P2E / 64, H_ / 64), 256, 0, stream>>>(
        W_in, Wi_hi, Wi_lo, H_, P2E);
    // 1) proj = x @ W_in   (M x 8192, K=2048); 1D grid 16*64 = 1024 tiles
    gemm3bf_k<<<(M_ / 128) * (P2E / 128), 256, 0, stream>>>(
        x_hi, x_lo, Wi_hi, Wi_lo, proj, H_, P2E);
    // 2) conv + SiLU
    conv_silu_k<<<(M_ * E_) / 256, 256, 0, stream>>>(proj, ck, cb, hc);
    // 3) ssm = hc @ W_x    (split-K=8, atomic)
    sgemm_k<64,32,16,4,2,2><<<dim3(SLD/32, M_/64, 8), 256, 0, stream>>>(
        hc, W_x, ssm, E_, SLD, SLD, nullptr, E_/8);
    // 4) dts = softplus(ssm[:, :128] @ W_dt + b_dt)
    sgemm_k<128,64,16,8,4,1><<<dim3(E_/64, M_/128, 1), 256, 0, stream>>>(
        ssm, W_dt, dts, SLD, E_, E_, b_dt, TR_);
    // transpose+decompose W_out (x region dead)
    wdecomp_t_k<<<dim3(H_ / 64, E_ / 64), 256, 0, stream>>>(
        W_out, Wo_hi, Wo_lo, E_, H_);
    // 5) chunked scan
    scan_p1_k<<<B_ * CH_ * (E_ / 256), 256, 0, stream>>>(
        hc, ssm, A_log, dts, Pbuf, Qbuf);
    scan_p3_k<<<B_ * CH_ * (E_ / 256), 256, 0, stream>>>(
        hc, ssm, proj, A_log, Dvec, dts, Pbuf, Qbuf, y_hi, y_lo);
    // 6) out = y @ W_out   (M x 2048, K=4096); 1D grid 16*16 = 256 tiles
    gemm3bf_k<<<(M_ / 128) * (H_ / 128), 256, 0, stream>>>(
        y_hi, y_lo, Wo_hi, Wo_lo, out, E_, H_);
  } else {
    // ---- fp32 fallback (round-1 pipeline) ----
    size_t base_f = (size_t)M_ * P2E + 2 * (size_t)M_ * E_ + (size_t)M_ * SLD;
    size_t need   = (base_f + (size_t)M_ * E_) * sizeof(float);
    float* yb = (ws_size >= need) ? (ssm + (size_t)M_ * SLD) : dts;
    sgemm_k<128,64,16,8,4,0><<<dim3(P2E/64, M_/128, 1), 256, 0, stream>>>(
        x_in, W_in, proj, H_, P2E, P2E, nullptr, H_);
    conv_silu_k<<<(M_ * E_) / 256, 256, 0, stream>>>(proj, ck, cb, hc);
    sgemm_k<64,32,16,4,2,2><<<dim3(SLD/32, M_/64, 8), 256, 0, stream>>>(
        hc, W_x, ssm, E_, SLD, SLD, nullptr, E_/8);
    sgemm_k<128,64,16,8,4,1><<<dim3(E_/64, M_/128, 1), 256, 0, stream>>>(
        ssm, W_dt, dts, SLD, E_, E_, b_dt, TR_);
    scan_serial_k<<<(B_ * E_) / 16, 256, 0, stream>>>(
        hc, ssm, proj, A_log, Dvec, dts, yb);
    sgemm_k<128,64,16,8,4,0><<<dim3(H_/64, M_/128, 1), 256, 0, stream>>>(
        yb, W_out, out, E_, H_, H_, nullptr, E_);
  }
}

// Round 6
// 778.179 us; speedup vs baseline: 1.0700x; 1.0700x over previous
//
#include <hip/hip_runtime.h>
#include <cstddef>
#include <cstdint>

// Problem constants (from reference): B,L,H,E,N,TR,K
constexpr int B_  = 2;
constexpr int L_  = 1024;
constexpr int H_  = 2048;
constexpr int E_  = 4096;
constexpr int N_  = 16;
constexpr int TR_ = 128;
constexpr int M_  = B_ * L_;        // 2048 token rows
constexpr int P2E = 2 * E_;         // 8192  (proj leading dim)
constexpr int SLD = TR_ + 2 * N_;   // 160   (ssm_p leading dim)
constexpr int CH_ = 32;             // scan chunks along L
constexpr int CL_ = L_ / CH_;       // 32 steps per chunk
constexpr int XKZ = 16;             // x-proj split-K factor

typedef unsigned short u16;
using short8 = __attribute__((ext_vector_type(8))) short;
using f32x4  = __attribute__((ext_vector_type(4))) float;

__device__ __forceinline__ float siluf(float x) { return x / (1.f + expf(-x)); }
__device__ __forceinline__ float silu_fast(float x) { return x / (1.f + __expf(-x)); }
__device__ __forceinline__ float softplusf(float x) {
  return fmaxf(x, 0.f) + log1pf(expf(-fabsf(x)));
}
__device__ __forceinline__ u16 f2bf(float x) {
  union { float f; uint32_t u; } v; v.f = x;
  uint32_t r = v.u + 0x7FFFu + ((v.u >> 16) & 1u);   // RNE
  return (u16)(r >> 16);
}
__device__ __forceinline__ float bf2f(u16 h) {
  union { uint32_t u; float f; } v; v.u = ((uint32_t)h) << 16; return v.f;
}
// async global->LDS, 16B per lane; dest = wave-uniform base + lane*16
__device__ __forceinline__ void gll16(const u16* g, u16* l) {
  __builtin_amdgcn_global_load_lds(
      (const __attribute__((address_space(1))) void*)(const void*)g,
      (__attribute__((address_space(3))) void*)(void*)l, 16, 0, 0);
}

// ---------------------------------------------------------------------------
// fp32 tiled GEMM (full-pipeline fallback only)
// ---------------------------------------------------------------------------
template<int BM, int BN, int BK, int TM, int TN, int EPI>
__global__ __launch_bounds__(256) void sgemm_k(
    const float* __restrict__ A, const float* __restrict__ B,
    float* __restrict__ C, int lda, int ldb, int ldc,
    const float* __restrict__ bias, int kchunk)
{
  __shared__ float As[BK][BM + 4];
  __shared__ float Bs[BK][BN];
  const int tid = threadIdx.x;
  const int tx  = tid & 15;
  const int ty  = tid >> 4;
  const int m0  = blockIdx.y * BM;
  const int n0  = blockIdx.x * BN;
  const int k00 = blockIdx.z * kchunk;

  float acc[TM][TN];
#pragma unroll
  for (int i = 0; i < TM; ++i)
#pragma unroll
    for (int j = 0; j < TN; ++j) acc[i][j] = 0.f;

  for (int k0 = k00; k0 < k00 + kchunk; k0 += BK) {
    constexpr int A4 = BM * BK / 4;
#pragma unroll
    for (int it = 0; it < (A4 + 255) / 256; ++it) {
      int i = it * 256 + tid;
      if ((A4 % 256 == 0) || (i < A4)) {
        int row = i / (BK / 4);
        int kc  = (i % (BK / 4)) * 4;
        float4 v = *reinterpret_cast<const float4*>(
            A + (size_t)(m0 + row) * lda + k0 + kc);
        As[kc + 0][row] = v.x; As[kc + 1][row] = v.y;
        As[kc + 2][row] = v.z; As[kc + 3][row] = v.w;
      }
    }
    constexpr int B4 = BK * BN / 4;
#pragma unroll
    for (int it = 0; it < (B4 + 255) / 256; ++it) {
      int i = it * 256 + tid;
      if ((B4 % 256 == 0) || (i < B4)) {
        int kr = i / (BN / 4);
        int nc = (i % (BN / 4)) * 4;
        *reinterpret_cast<float4*>(&Bs[kr][nc]) =
            *reinterpret_cast<const float4*>(
                B + (size_t)(k0 + kr) * ldb + n0 + nc);
      }
    }
    __syncthreads();
#pragma unroll
    for (int k = 0; k < BK; ++k) {
      float a[TM], bb[TN];
      const float* ap = &As[k][ty * TM];
      if constexpr (TM == 8) {
        float4 a0 = *reinterpret_cast<const float4*>(ap);
        float4 a1 = *reinterpret_cast<const float4*>(ap + 4);
        a[0]=a0.x; a[1]=a0.y; a[2]=a0.z; a[3]=a0.w;
        a[4]=a1.x; a[5]=a1.y; a[6]=a1.z; a[7]=a1.w;
      } else {
        float4 a0 = *reinterpret_cast<const float4*>(ap);
        a[0]=a0.x; a[1]=a0.y; a[2]=a0.z; a[3]=a0.w;
      }
      const float* bp = &Bs[k][tx * TN];
      if constexpr (TN == 4) {
        float4 b0 = *reinterpret_cast<const float4*>(bp);
        bb[0]=b0.x; bb[1]=b0.y; bb[2]=b0.z; bb[3]=b0.w;
      } else {
        float2 b0 = *reinterpret_cast<const float2*>(bp);
        bb[0]=b0.x; bb[1]=b0.y;
      }
#pragma unroll
      for (int i = 0; i < TM; ++i)
#pragma unroll
        for (int j = 0; j < TN; ++j) acc[i][j] = fmaf(a[i], bb[j], acc[i][j]);
    }
    __syncthreads();
  }

#pragma unroll
  for (int i = 0; i < TM; ++i) {
    int row = m0 + ty * TM + i;
    float* crow = C + (size_t)row * ldc + n0 + tx * TN;
    if constexpr (EPI == 2) {
#pragma unroll
      for (int j = 0; j < TN; ++j) atomicAdd(&crow[j], acc[i][j]);
    } else if constexpr (EPI == 1) {
      const float* brow = bias + n0 + tx * TN;
      float4 v;
      v.x = softplusf(acc[i][0] + brow[0]);
      v.y = softplusf(acc[i][1] + brow[1]);
      v.z = softplusf(acc[i][2] + brow[2]);
      v.w = softplusf(acc[i][3] + brow[3]);
      *reinterpret_cast<float4*>(crow) = v;
    } else {
      if constexpr (TN == 4) {
        float4 v; v.x=acc[i][0]; v.y=acc[i][1]; v.z=acc[i][2]; v.w=acc[i][3];
        *reinterpret_cast<float4*>(crow) = v;
      } else {
#pragma unroll
        for (int j = 0; j < TN; ++j) crow[j] = acc[i][j];
      }
    }
  }
}

// ---------------------------------------------------------------------------
// fp32 -> (bf16 hi, bf16 lo), row-major passthrough. 4 floats / thread.
// ---------------------------------------------------------------------------
__global__ __launch_bounds__(256) void decomp_k(
    const float* __restrict__ in, u16* __restrict__ hi, u16* __restrict__ lo,
    int n4)
{
  int i = blockIdx.x * 256 + threadIdx.x;
  if (i >= n4) return;
  float4 v = *reinterpret_cast<const float4*>(in + (size_t)i * 4);
  u16 h[4], l[4];
  float x[4] = {v.x, v.y, v.z, v.w};
#pragma unroll
  for (int j = 0; j < 4; ++j) {
    h[j] = f2bf(x[j]);
    l[j] = f2bf(x[j] - bf2f(h[j]));
  }
  uint32_t h0 = h[0] | ((uint32_t)h[1] << 16), h1 = h[2] | ((uint32_t)h[3] << 16);
  uint32_t l0 = l[0] | ((uint32_t)l[1] << 16), l1 = l[2] | ((uint32_t)l[3] << 16);
  *reinterpret_cast<uint2*>(hi + (size_t)i * 4) = make_uint2(h0, h1);
  *reinterpret_cast<uint2*>(lo + (size_t)i * 4) = make_uint2(l0, l1);
}

// ---------------------------------------------------------------------------
// W[KD][ND] fp32 -> Wt_hi/Wt_lo [ND][KD] bf16 (transpose + decompose).
// GUARD: ND may not be a multiple of 64 (col-guarded loads/stores).
// ---------------------------------------------------------------------------
template<bool GUARD>
__global__ __launch_bounds__(256) void wdecomp_t_k(
    const float* __restrict__ W, u16* __restrict__ Whi, u16* __restrict__ Wlo,
    int KD, int ND)
{
  __shared__ float T[64][69];
  const int t  = threadIdx.x;
  const int n0 = blockIdx.x * 64;
  const int k0 = blockIdx.y * 64;
#pragma unroll
  for (int it = 0; it < 4; ++it) {
    int f  = it * 256 + t;
    int kk = f >> 4;
    int c  = (f & 15) * 4;
    if (!GUARD || (n0 + c < ND)) {
      float4 v = *reinterpret_cast<const float4*>(
          W + (size_t)(k0 + kk) * ND + n0 + c);
      T[kk][c] = v.x; T[kk][c+1] = v.y; T[kk][c+2] = v.z; T[kk][c+3] = v.w;
    } else {
      T[kk][c] = 0.f; T[kk][c+1] = 0.f; T[kk][c+2] = 0.f; T[kk][c+3] = 0.f;
    }
  }
  __syncthreads();
  const int nn   = t >> 2;
  const int kseg = (t & 3) * 16;
  if (GUARD && (n0 + nn >= ND)) return;
  const size_t off = (size_t)(n0 + nn) * KD + k0 + kseg;
#pragma unroll
  for (int half = 0; half < 2; ++half) {
    uint32_t hp[4], lp[4];
#pragma unroll
    for (int jj = 0; jj < 4; ++jj) {
      float x0 = T[kseg + half * 8 + jj * 2 + 0][nn];
      float x1 = T[kseg + half * 8 + jj * 2 + 1][nn];
      u16 h0 = f2bf(x0), h1 = f2bf(x1);
      u16 l0 = f2bf(x0 - bf2f(h0)), l1 = f2bf(x1 - bf2f(h1));
      hp[jj] = h0 | ((uint32_t)h1 << 16);
      lp[jj] = l0 | ((uint32_t)l1 << 16);
    }
    *reinterpret_cast<uint4*>(Whi + off + half * 8) =
        make_uint4(hp[0], hp[1], hp[2], hp[3]);
    *reinterpret_cast<uint4*>(Wlo + off + half * 8) =
        make_uint4(lp[0], lp[1], lp[2], lp[3]);
  }
}

// ---------------------------------------------------------------------------
// Split-bf16 MFMA GEMM: C[M][N] fp32 = A[M][K] x Bt[N][K]^T via
//   Ah*Bh + Ah*Bl + Al*Bh (3x mfma_f32_16x16x32_bf16, fp32 accumulate).
// 128x128 tile, BK=32, global_load_lds staging, both-sides XOR swizzle,
// bijective XCD swizzle (grid%8==0, nTm=16 at every call site).
// EPI: 0 = plain store; 1 = softplus(acc + bias[col]).
// ---------------------------------------------------------------------------
template<int EPI>
__global__ __launch_bounds__(256) void gemm3bf_k(
    const u16* __restrict__ Ah, const u16* __restrict__ Al,
    const u16* __restrict__ Bh, const u16* __restrict__ Bl,
    float* __restrict__ C, int K, int ldc, const float* __restrict__ bias)
{
  __shared__ __align__(16) u16 sAh[128 * 32];
  __shared__ __align__(16) u16 sAl[128 * 32];
  __shared__ __align__(16) u16 sBh[128 * 32];
  __shared__ __align__(16) u16 sBl[128 * 32];

  const int tid  = threadIdx.x;
  const int lane = tid & 63;
  const int wid  = tid >> 6;
  const int wr   = wid >> 1, wc = wid & 1;

  const int nwg = gridDim.x;
  const int q8  = nwg >> 3;
  const int wg  = (blockIdx.x & 7) * q8 + (blockIdx.x >> 3);
  const int tm  = wg & 15;          // nTm = M_/128 = 16 (all call sites)
  const int tn  = wg >> 4;
  const int m0  = tm * 128;
  const int n0  = tn * 128;

  const int dr = lane >> 2;
  const int sw = (lane & 3) ^ ((lane >> 3) & 3);
  const int r1 = wid * 16 + dr;
  const int r2 = r1 + 64;

  const u16* ga1 = Ah + (size_t)(m0 + r1) * K + sw * 8;
  const u16* ga2 = Ah + (size_t)(m0 + r2) * K + sw * 8;
  const u16* gl1 = Al + (size_t)(m0 + r1) * K + sw * 8;
  const u16* gl2 = Al + (size_t)(m0 + r2) * K + sw * 8;
  const u16* gb1 = Bh + (size_t)(n0 + r1) * K + sw * 8;
  const u16* gb2 = Bh + (size_t)(n0 + r2) * K + sw * 8;
  const u16* gc1 = Bl + (size_t)(n0 + r1) * K + sw * 8;
  const u16* gc2 = Bl + (size_t)(n0 + r2) * K + sw * 8;

  u16* dA1 = sAh + (wid * 16) * 32;
  u16* dA2 = sAh + (64 + wid * 16) * 32;
  u16* dL1 = sAl + (wid * 16) * 32;
  u16* dL2 = sAl + (64 + wid * 16) * 32;
  u16* dB1 = sBh + (wid * 16) * 32;
  u16* dB2 = sBh + (64 + wid * 16) * 32;
  u16* dC1 = sBl + (wid * 16) * 32;
  u16* dC2 = sBl + (64 + wid * 16) * 32;

  const int fr = lane & 15;
  const int ph = (lane >> 4) ^ ((fr >> 1) & 3);
  const int offA = (wr * 64 + fr) * 32 + ph * 8;
  const int offB = (wc * 64 + fr) * 32 + ph * 8;

  f32x4 acc[4][4] = {};

  for (int k0 = 0; k0 < K; k0 += 32) {
    __syncthreads();
    gll16(ga1 + k0, dA1);  gll16(ga2 + k0, dA2);
    gll16(gl1 + k0, dL1);  gll16(gl2 + k0, dL2);
    gll16(gb1 + k0, dB1);  gll16(gb2 + k0, dB2);
    gll16(gc1 + k0, dC1);  gll16(gc2 + k0, dC2);
    __syncthreads();

    short8 bhf[4], blf[4];
#pragma unroll
    for (int nc = 0; nc < 4; ++nc) {
      bhf[nc] = *reinterpret_cast<const short8*>(&sBh[offB + nc * 512]);
      blf[nc] = *reinterpret_cast<const short8*>(&sBl[offB + nc * 512]);
    }
#pragma unroll
    for (int mr = 0; mr < 4; ++mr) {
      short8 ahf = *reinterpret_cast<const short8*>(&sAh[offA + mr * 512]);
      short8 alf = *reinterpret_cast<const short8*>(&sAl[offA + mr * 512]);
#pragma unroll
      for (int nc = 0; nc < 4; ++nc) {
        acc[mr][nc] = __builtin_amdgcn_mfma_f32_16x16x32_bf16(ahf, bhf[nc], acc[mr][nc], 0, 0, 0);
        acc[mr][nc] = __builtin_amdgcn_mfma_f32_16x16x32_bf16(ahf, blf[nc], acc[mr][nc], 0, 0, 0);
        acc[mr][nc] = __builtin_amdgcn_mfma_f32_16x16x32_bf16(alf, bhf[nc], acc[mr][nc], 0, 0, 0);
      }
    }
  }

#pragma unroll
  for (int mr = 0; mr < 4; ++mr) {
    const int rowb = m0 + wr * 64 + mr * 16 + ((lane >> 4) << 2);
#pragma unroll
    for (int nc = 0; nc < 4; ++nc) {
      const int col = n0 + wc * 64 + nc * 16 + fr;
      float* cp = C + (size_t)rowb * ldc + col;
      if constexpr (EPI == 1) {
        const float bv = bias[col];
#pragma unroll
        for (int i = 0; i < 4; ++i)
          cp[(size_t)i * ldc] = softplusf(acc[mr][nc][i] + bv);
      } else {
#pragma unroll
        for (int i = 0; i < 4; ++i) cp[(size_t)i * ldc] = acc[mr][nc][i];
      }
    }
  }
}

// ---------------------------------------------------------------------------
// x-proj: part[kz][M][160] = hc[M][E] @ Wx[E][160], split-K=XKZ, 3-term bf16.
// Block: 128 rows x all 160 cols; 4 waves, wave = 32 rows x 160 cols.
// ---------------------------------------------------------------------------
__global__ __launch_bounds__(256) void gemmx_k(
    const u16* __restrict__ Ah, const u16* __restrict__ Al,
    const u16* __restrict__ Bh, const u16* __restrict__ Bl,
    float* __restrict__ part)
{
  constexpr int LDK = 40;
  __shared__ __align__(16) u16 sAh[128 * LDK];
  __shared__ __align__(16) u16 sAl[128 * LDK];
  __shared__ __align__(16) u16 sBh[160 * LDK];
  __shared__ __align__(16) u16 sBl[160 * LDK];

  const int tid  = threadIdx.x;
  const int lane = tid & 63;
  const int wid  = tid >> 6;
  const int mt   = blockIdx.x & 15;
  const int kz   = blockIdx.x >> 4;
  const int m0   = mt * 128;
  const int k00  = kz * (E_ / XKZ);
  const int fr   = lane & 15;
  const int fk   = (lane >> 4) * 8;

  f32x4 acc[2][10] = {};

  for (int k0 = k00; k0 < k00 + E_ / XKZ; k0 += 32) {
    __syncthreads();
#pragma unroll
    for (int it = 0; it < 2; ++it) {
      int i = it * 256 + tid;
      int row = i >> 2, c = (i & 3) * 8;
      size_t go = (size_t)(m0 + row) * E_ + k0 + c;
      *reinterpret_cast<uint4*>(&sAh[row * LDK + c]) =
          *reinterpret_cast<const uint4*>(Ah + go);
      *reinterpret_cast<uint4*>(&sAl[row * LDK + c]) =
          *reinterpret_cast<const uint4*>(Al + go);
    }
#pragma unroll
    for (int it = 0; it < 3; ++it) {
      int i = it * 256 + tid;
      if (i < 640) {
        int row = i >> 2, c = (i & 3) * 8;
        size_t go = (size_t)row * E_ + k0 + c;
        *reinterpret_cast<uint4*>(&sBh[row * LDK + c]) =
            *reinterpret_cast<const uint4*>(Bh + go);
        *reinterpret_cast<uint4*>(&sBl[row * LDK + c]) =
            *reinterpret_cast<const uint4*>(Bl + go);
      }
    }
    __syncthreads();

    short8 a_h[2], a_l[2];
#pragma unroll
    for (int mr = 0; mr < 2; ++mr) {
      int row = wid * 32 + mr * 16 + fr;
      a_h[mr] = *reinterpret_cast<const short8*>(&sAh[row * LDK + fk]);
      a_l[mr] = *reinterpret_cast<const short8*>(&sAl[row * LDK + fk]);
    }
#pragma unroll
    for (int nc = 0; nc < 10; ++nc) {
      int row = nc * 16 + fr;
      short8 b_h = *reinterpret_cast<const short8*>(&sBh[row * LDK + fk]);
      short8 b_l = *reinterpret_cast<const short8*>(&sBl[row * LDK + fk]);
#pragma unroll
      for (int mr = 0; mr < 2; ++mr) {
        acc[mr][nc] = __builtin_amdgcn_mfma_f32_16x16x32_bf16(a_h[mr], b_h, acc[mr][nc], 0, 0, 0);
        acc[mr][nc] = __builtin_amdgcn_mfma_f32_16x16x32_bf16(a_h[mr], b_l, acc[mr][nc], 0, 0, 0);
        acc[mr][nc] = __builtin_amdgcn_mfma_f32_16x16x32_bf16(a_l[mr], b_h, acc[mr][nc], 0, 0, 0);
      }
    }
  }

#pragma unroll
  for (int mr = 0; mr < 2; ++mr) {
    const int rowb = m0 + wid * 32 + mr * 16 + ((lane >> 4) << 2);
#pragma unroll
    for (int nc = 0; nc < 10; ++nc) {
      const int col = nc * 16 + fr;
      float* pp = part + ((size_t)kz * M_ + rowb) * SLD + col;
#pragma unroll
      for (int i = 0; i < 4; ++i) pp[(size_t)i * SLD] = acc[mr][nc][i];
    }
  }
}

// reduce XKZ partials -> ssm fp32; also decompose dt cols to sdt hi/lo
__global__ __launch_bounds__(256) void xreduce_k(
    const float* __restrict__ part, float* __restrict__ ssm,
    u16* __restrict__ sdt_hi, u16* __restrict__ sdt_lo)
{
  const int t = blockIdx.x * 256 + threadIdx.x;   // < M_*SLD
  float s = 0.f;
#pragma unroll
  for (int z = 0; z < XKZ; ++z) s += part[(size_t)z * M_ * SLD + t];
  ssm[t] = s;
  const int col = t % SLD;
  if (col < TR_) {
    const int m = t / SLD;
    const u16 hv = f2bf(s);
    sdt_hi[(size_t)m * TR_ + col] = hv;
    sdt_lo[(size_t)m * TR_ + col] = f2bf(s - bf2f(hv));
  }
}

// ---------------------------------------------------------------------------
// Depthwise causal conv1d (K=4) + bias + SiLU; emits fp32 + bf16 hi/lo
// ---------------------------------------------------------------------------
__global__ __launch_bounds__(256) void conv_silu_k(
    const float* __restrict__ proj, const float* __restrict__ ck,
    const float* __restrict__ cb, float* __restrict__ hc,
    u16* __restrict__ hchi, u16* __restrict__ hclo)
{
  const int idx = blockIdx.x * 256 + threadIdx.x;
  const int e = idx & (E_ - 1);
  const int m = idx >> 12;
  const int l = m & (L_ - 1);
  const float c0 = ck[e * 4 + 0], c1 = ck[e * 4 + 1];
  const float c2 = ck[e * 4 + 2], c3 = ck[e * 4 + 3];
  const float* pcol = proj + (size_t)m * P2E + e;
  float acc = cb[e];
  if (l >= 3) acc = fmaf(pcol[-3 * P2E], c0, acc);
  if (l >= 2) acc = fmaf(pcol[-2 * P2E], c1, acc);
  if (l >= 1) acc = fmaf(pcol[-1 * P2E], c2, acc);
  acc = fmaf(pcol[0], c3, acc);
  const float r = siluf(acc);
  const size_t o = (size_t)m * E_ + e;
  hc[o] = r;
  const u16 hv = f2bf(r);
  hchi[o] = hv;
  hclo[o] = f2bf(r - bf2f(hv));
}

// ---------------------------------------------------------------------------
// Chunked selective scan, thread = e-channel, all N=16 states in registers.
// ---------------------------------------------------------------------------
__global__ __launch_bounds__(256) void scan_p1_k(
    const float* __restrict__ hc, const float* __restrict__ ssm,
    const float* __restrict__ A_log, const float* __restrict__ dts,
    float* __restrict__ Pbuf, float* __restrict__ Qbuf)
{
  __shared__ float sB[CL_][16];
  const int tid = threadIdx.x;
  const int bid = blockIdx.x;
  const int e   = ((bid & 15) << 8) + tid;
  const int c   = (bid >> 4) & (CH_ - 1);
  const int b   = bid >> 9;
  const int m0  = b * L_ + c * CL_;

  if (tid < CL_ * 4) {
    int s = tid >> 2, q = tid & 3;
    *reinterpret_cast<float4*>(&sB[s][q * 4]) =
        *reinterpret_cast<const float4*>(
            &ssm[(size_t)(m0 + s) * SLD + TR_ + q * 4]);
  }
  __syncthreads();

  float Aen[N_];
#pragma unroll
  for (int q = 0; q < 4; ++q) {
    float4 av = *reinterpret_cast<const float4*>(&A_log[e * N_ + q * 4]);
    Aen[q*4+0] = -expf(av.x); Aen[q*4+1] = -expf(av.y);
    Aen[q*4+2] = -expf(av.z); Aen[q*4+3] = -expf(av.w);
  }

  float P[N_], Q[N_];
#pragma unroll
  for (int n = 0; n < N_; ++n) { P[n] = 1.f; Q[n] = 0.f; }

  float dt_c = dts[(size_t)m0 * E_ + e];
  float h_c  = hc [(size_t)m0 * E_ + e];
  for (int s = 0; s < CL_; ++s) {
    const int sn = (s + 1 < CL_) ? s + 1 : s;
    const float dt_n = dts[(size_t)(m0 + sn) * E_ + e];
    const float h_n  = hc [(size_t)(m0 + sn) * E_ + e];
    const float dth = dt_c * h_c;
#pragma unroll
    for (int q = 0; q < 4; ++q) {
      const float4 bv = *reinterpret_cast<const float4*>(&sB[s][q * 4]);
      const float bx[4] = {bv.x, bv.y, bv.z, bv.w};
#pragma unroll
      for (int j = 0; j < 4; ++j) {
        const int n = q * 4 + j;
        const float a = __expf(dt_c * Aen[n]);
        Q[n] = fmaf(a, Q[n], dth * bx[j]);
        P[n] *= a;
      }
    }
    dt_c = dt_n; h_c = h_n;
  }

  const size_t ob = (((size_t)b * CH_ + c) * N_) * E_ + e;
#pragma unroll
  for (int n = 0; n < N_; ++n) {
    Pbuf[ob + (size_t)n * E_] = P[n];
    Qbuf[ob + (size_t)n * E_] = Q[n];
  }
}

__global__ __launch_bounds__(256) void scan_p3_k(
    const float* __restrict__ hc, const float* __restrict__ ssm,
    const float* __restrict__ proj, const float* __restrict__ A_log,
    const float* __restrict__ Dvec, const float* __restrict__ dts,
    const float* __restrict__ Pbuf, const float* __restrict__ Qbuf,
    u16* __restrict__ yhi, u16* __restrict__ ylo)
{
  __shared__ float sBC[CL_][32];
  const int tid = threadIdx.x;
  const int bid = blockIdx.x;
  const int e   = ((bid & 15) << 8) + tid;
  const int c   = (bid >> 4) & (CH_ - 1);
  const int b   = bid >> 9;
  const int m0  = b * L_ + c * CL_;

  {
    int s = tid >> 3, q = tid & 7;
    *reinterpret_cast<float4*>(&sBC[s][q * 4]) =
        *reinterpret_cast<const float4*>(
            &ssm[(size_t)(m0 + s) * SLD + TR_ + q * 4]);
  }
  __syncthreads();

  float Aen[N_];
#pragma unroll
  for (int q = 0; q < 4; ++q) {
    float4 av = *reinterpret_cast<const float4*>(&A_log[e * N_ + q * 4]);
    Aen[q*4+0] = -expf(av.x); Aen[q*4+1] = -expf(av.y);
    Aen[q*4+2] = -expf(av.z); Aen[q*4+3] = -expf(av.w);
  }
  const float De = Dvec[e];

  float st[N_];
#pragma unroll
  for (int n = 0; n < N_; ++n) st[n] = 0.f;
  for (int cc = 0; cc < c; ++cc) {
    const size_t ob = (((size_t)b * CH_ + cc) * N_) * E_ + e;
#pragma unroll
    for (int n = 0; n < N_; ++n)
      st[n] = fmaf(Pbuf[ob + (size_t)n * E_], st[n], Qbuf[ob + (size_t)n * E_]);
  }

  float dt_c = dts[(size_t)m0 * E_ + e];
  float h_c  = hc [(size_t)m0 * E_ + e];
  float g_c  = proj[(size_t)m0 * P2E + E_ + e];
  for (int s = 0; s < CL_; ++s) {
    const int sn = (s + 1 < CL_) ? s + 1 : s;
    const float dt_n = dts[(size_t)(m0 + sn) * E_ + e];
    const float h_n  = hc [(size_t)(m0 + sn) * E_ + e];
    const float g_n  = proj[(size_t)(m0 + sn) * P2E + E_ + e];
    const float dth = dt_c * h_c;
    float y = h_c * De;
#pragma unroll
    for (int q = 0; q < 4; ++q) {
      const float4 bv = *reinterpret_cast<const float4*>(&sBC[s][q * 4]);
      const float4 cv = *reinterpret_cast<const float4*>(&sBC[s][16 + q * 4]);
      const float bx[4] = {bv.x, bv.y, bv.z, bv.w};
      const float cx[4] = {cv.x, cv.y, cv.z, cv.w};
#pragma unroll
      for (int j = 0; j < 4; ++j) {
        const int n = q * 4 + j;
        const float a = __expf(dt_c * Aen[n]);
        st[n] = fmaf(a, st[n], dth * bx[j]);
        y = fmaf(st[n], cx[j], y);
      }
    }
    const float res = y * silu_fast(g_c);
    const u16 hv = f2bf(res);
    const size_t yo = (size_t)(m0 + s) * E_ + e;
    yhi[yo] = hv;
    ylo[yo] = f2bf(res - bf2f(hv));
    dt_c = dt_n; h_c = h_n; g_c = g_n;
  }
}

// fp32-output serial scan (fallback path only)
__global__ __launch_bounds__(256) void scan_serial_k(
    const float* __restrict__ hc, const float* __restrict__ ssm,
    const float* __restrict__ proj, const float* __restrict__ A_log,
    const float* __restrict__ Dvec, const float* __restrict__ dts,
    float* __restrict__ yf)
{
  const int tid = threadIdx.x;
  const int n  = tid & 15;
  const int ge = blockIdx.x * 16 + (tid >> 4);
  const int b  = ge >> 12;
  const int e  = ge & (E_ - 1);
  const float Aen = -expf(A_log[e * N_ + n]);
  const float De  = Dvec[e];
  float state = 0.f;
  const int mbase = b * L_;
  for (int l = 0; l < L_; ++l) {
    const int m = mbase + l;
    const float dt = dts[(size_t)m * E_ + e];
    const float h  = hc[(size_t)m * E_ + e];
    const float Bm = ssm[(size_t)m * SLD + TR_ + n];
    const float Cm = ssm[(size_t)m * SLD + TR_ + N_ + n];
    state = fmaf(expf(dt * Aen), state, dt * Bm * h);
    float yp = state * Cm;
    yp += __shfl_xor(yp, 1);
    yp += __shfl_xor(yp, 2);
    yp += __shfl_xor(yp, 4);
    yp += __shfl_xor(yp, 8);
    const float g   = proj[(size_t)m * P2E + E_ + e];
    const float res = (yp + h * De) * siluf(g);
    if (n == 0) yf[(size_t)m * E_ + e] = res;
  }
}

// ---------------------------------------------------------------------------
extern "C" void kernel_launch(void* const* d_in, const int* in_sizes, int n_in,
                              void* d_out, int out_size, void* d_ws, size_t ws_size,
                              hipStream_t stream)
{
  const float* x_in  = (const float*)d_in[0];
  const float* W_in  = (const float*)d_in[1];
  const float* ck    = (const float*)d_in[2];
  const float* cb    = (const float*)d_in[3];
  const float* W_x   = (const float*)d_in[4];
  const float* W_dt  = (const float*)d_in[5];
  const float* b_dt  = (const float*)d_in[6];
  const float* W_out = (const float*)d_in[7];
  const float* A_log = (const float*)d_in[8];
  const float* Dvec  = (const float*)d_in[9];
  float* out = (float*)d_out;
  float* ws  = (float*)d_ws;

  // common fp32 workspace
  float* proj = ws;                               // 16,777,216 f (64 MB)
  float* hc   = proj + (size_t)M_ * P2E;          // 8,388,608  f (32 MB)
  float* dts  = hc   + (size_t)M_ * E_;           // 8,388,608  f (32 MB)
  float* ssm  = dts  + (size_t)M_ * E_;           // 327,680    f (1.25 MB)

  // bf16 regions, lifetime-aliased (all offsets in u16 elements):
  //  regA (32 MB): x_hi/x_lo (dead after in-proj)  -> Wo_hi/Wo_lo
  //  regB (64 MB): Wi_hi/Wi_lo (dead after in-proj) ->
  //     [0,32MB):  hc_hi/hc_lo (conv..gemmx)  -> y_hi/y_lo (scan_p3..out-proj)
  //     [32,53MB): part (gemmx..xreduce)      -> Pbuf/Qbuf [32,64MB) (scans)
  //     [54.5MB+): Wxt/Wdtt/sdt hi+lo (post-in-proj .. gemmdt)
  u16* regA  = (u16*)(ssm + (size_t)M_ * SLD);
  u16* x_hi  = regA;
  u16* x_lo  = regA + (size_t)M_ * H_;
  u16* Wo_hi = regA;
  u16* Wo_lo = regA + (size_t)H_ * E_;
  u16* regB  = regA + 16777216;
  u16* Wi_hi = regB;
  u16* Wi_lo = regB + (size_t)P2E * H_;
  u16* hc_hi = regB;
  u16* hc_lo = regB + (size_t)M_ * E_;
  u16* y_hi  = regB;
  u16* y_lo  = regB + (size_t)M_ * E_;
  float* part = (float*)(regB + 16777216);         // XKZ*M_*SLD = 5,242,880 f
  float* Pbuf = (float*)(regB + 16777216);         // 4,194,304 f (16 MB)
  float* Qbuf = Pbuf + (size_t)B_ * CH_ * E_ * N_; // 4,194,304 f (16 MB)
  u16* su      = regB + 16777216 + 2 * (size_t)XKZ * M_ * SLD;
  u16* Wxt_hi  = su;                               // 160*4096 = 655,360
  u16* Wxt_lo  = su + 655360;
  u16* Wdtt_hi = su + 1310720;                     // 4096*128 = 524,288
  u16* Wdtt_lo = su + 1835008;
  u16* sdt_hi  = su + 2359296;                     // 2048*128 = 262,144
  u16* sdt_lo  = su + 2621440;

  const size_t need_bf =
      ((size_t)M_ * P2E + 2 * (size_t)M_ * E_ + (size_t)M_ * SLD) * 4 +
      (16777216ULL + 33554432ULL) * 2;            // = 236,191,744 B

  if (ws_size >= need_bf) {
    // ---- split-bf16 MFMA path (all GEMMs) + register-state chunked scan ----
    decomp_k<<<(M_ * H_ / 4 + 255) / 256, 256, 0, stream>>>(
        x_in, x_hi, x_lo, M_ * H_ / 4);
    wdecomp_t_k<false><<<dim3(P2E / 64, H_ / 64), 256, 0, stream>>>(
        W_in, Wi_hi, Wi_lo, H_, P2E);
    // 1) proj = x @ W_in   (M x 8192, K=2048)
    gemm3bf_k<0><<<(M_ / 128) * (P2E / 128), 256, 0, stream>>>(
        x_hi, x_lo, Wi_hi, Wi_lo, proj, H_, P2E, nullptr);
    // 2) conv + SiLU  -> hc fp32 + bf16 hi/lo     (Wi region dead now)
    conv_silu_k<<<(M_ * E_) / 256, 256, 0, stream>>>(
        proj, ck, cb, hc, hc_hi, hc_lo);
    // small weight transforms (must run after in-proj: they overwrite Wi_lo)
    wdecomp_t_k<true><<<dim3(3, E_ / 64), 256, 0, stream>>>(
        W_x, Wxt_hi, Wxt_lo, E_, SLD);
    wdecomp_t_k<false><<<dim3(E_ / 64, TR_ / 64), 256, 0, stream>>>(
        W_dt, Wdtt_hi, Wdtt_lo, TR_, E_);
    // 3) x-proj: partials + reduce (also emits sdt hi/lo)
    gemmx_k<<<16 * XKZ, 256, 0, stream>>>(
        hc_hi, hc_lo, Wxt_hi, Wxt_lo, part);
    xreduce_k<<<(M_ * SLD) / 256, 256, 0, stream>>>(
        part, ssm, sdt_hi, sdt_lo);
    // 4) dts = softplus(sdt @ W_dt^T + b_dt)   (M x 4096, K=128)
    gemm3bf_k<1><<<(M_ / 128) * (E_ / 128), 256, 0, stream>>>(
        sdt_hi, sdt_lo, Wdtt_hi, Wdtt_lo, dts, TR_, E_, b_dt);
    // transpose+decompose W_out (x region dead)
    wdecomp_t_k<false><<<dim3(H_ / 64, E_ / 64), 256, 0, stream>>>(
        W_out, Wo_hi, Wo_lo, E_, H_);
    // 5) chunked scan
    scan_p1_k<<<B_ * CH_ * (E_ / 256), 256, 0, stream>>>(
        hc, ssm, A_log, dts, Pbuf, Qbuf);
    scan_p3_k<<<B_ * CH_ * (E_ / 256), 256, 0, stream>>>(
        hc, ssm, proj, A_log, Dvec, dts, Pbuf, Qbuf, y_hi, y_lo);
    // 6) out = y @ W_out   (M x 2048, K=4096)
    gemm3bf_k<0><<<(M_ / 128) * (H_ / 128), 256, 0, stream>>>(
        y_hi, y_lo, Wo_hi, Wo_lo, out, E_, H_, nullptr);
  } else {
    // ---- fp32 fallback (round-1 pipeline) ----
    hipMemsetAsync(ssm, 0, (size_t)M_ * SLD * sizeof(float), stream);
    size_t base_f = (size_t)M_ * P2E + 2 * (size_t)M_ * E_ + (size_t)M_ * SLD;
    size_t need   = (base_f + (size_t)M_ * E_) * sizeof(float);
    float* yb = (ws_size >= need) ? (ssm + (size_t)M_ * SLD) : dts;
    sgemm_k<128,64,16,8,4,0><<<dim3(P2E/64, M_/128, 1), 256, 0, stream>>>(
        x_in, W_in, proj, H_, P2E, P2E, nullptr, H_);
    conv_silu_k<<<(M_ * E_) / 256, 256, 0, stream>>>(
        proj, ck, cb, hc, (u16*)(ssm + (size_t)M_ * SLD),
        (u16*)(ssm + (size_t)M_ * SLD) + (size_t)M_ * E_);
    sgemm_k<64,32,16,4,2,2><<<dim3(SLD/32, M_/64, 8), 256, 0, stream>>>(
        hc, W_x, ssm, E_, SLD, SLD, nullptr, E_/8);
    sgemm_k<128,64,16,8,4,1><<<dim3(E_/64, M_/128, 1), 256, 0, stream>>>(
        ssm, W_dt, dts, SLD, E_, E_, b_dt, TR_);
    scan_serial_k<<<(B_ * E_) / 16, 256, 0, stream>>>(
        hc, ssm, proj, A_log, Dvec, dts, yb);
    sgemm_k<128,64,16,8,4,0><<<dim3(H_/64, M_/128, 1), 256, 0, stream>>>(
        yb, W_out, out, E_, H_, H_, nullptr, E_);
  }
}